// Round 4
// baseline (187.035 us; speedup 1.0000x reference)
//
#include <hip/hip_runtime.h>
#include <hip/hip_bf16.h>
#include <hip/hip_fp16.h>

typedef _Float16 f16x8 __attribute__((ext_vector_type(8)));
typedef _Float16 f16x4 __attribute__((ext_vector_type(4)));
typedef _Float16 f16x2 __attribute__((ext_vector_type(2)));
typedef float f32x4 __attribute__((ext_vector_type(4)));
typedef float f32x16 __attribute__((ext_vector_type(16)));
typedef unsigned int u32x4 __attribute__((ext_vector_type(4)));

#define MFMA16(a, b, c) __builtin_amdgcn_mfma_f32_16x16x32_f16(a, b, c, 0, 0, 0)
#define MFMA32(a, b, c) __builtin_amdgcn_mfma_f32_32x32x16_f16(a, b, c, 0, 0, 0)

// log2(e) / sqrt(1024)
#define C1 0.045084220027780106f

// ---------------------------------------------------------------------------
// convert f32 -> fp16 for Q, K, Wq, Wk, Wv into one contiguous ws region
// ---------------------------------------------------------------------------
__global__ void cvt_all(const float* __restrict__ Q, const float* __restrict__ K,
                        const float* __restrict__ Wq, const float* __restrict__ Wk,
                        const float* __restrict__ Wv, _Float16* __restrict__ dst) {
    int i = blockIdx.x * blockDim.x + threadIdx.x;  // i indexes groups of 8 f32
    const float* s;
    int off;
    if (i < 524288)       { s = Q;  off = 0;       }
    else if (i < 1048576) { s = K;  off = 524288;  }
    else if (i < 1179648) { s = Wq; off = 1048576; }
    else if (i < 1310720) { s = Wk; off = 1179648; }
    else                  { s = Wv; off = 1310720; }
    int j = i - off;
    float4 a = ((const float4*)s)[2 * j];
    float4 b = ((const float4*)s)[2 * j + 1];
    f16x8 h;
    h[0] = (_Float16)a.x; h[1] = (_Float16)a.y; h[2] = (_Float16)a.z; h[3] = (_Float16)a.w;
    h[4] = (_Float16)b.x; h[5] = (_Float16)b.y; h[6] = (_Float16)b.z; h[7] = (_Float16)b.w;
    ((f16x8*)dst)[i] = h;
}

// ---------------------------------------------------------------------------
// projection GEMM (unchanged): C[m,n] = A[m,:]·W[n,:] + bias[n]
// z=0: q, z=1: k, z=2: v written transposed as vT[b][h][d][n]
// ---------------------------------------------------------------------------
__device__ __forceinline__ void gl_lds16(const void* g, void* l) {
    __builtin_amdgcn_global_load_lds(
        (const __attribute__((address_space(1))) void*)g,
        (__attribute__((address_space(3))) void*)l, 16, 0, 0);
}

__global__ __launch_bounds__(256) void proj_gemm(
    const _Float16* __restrict__ Qh, const _Float16* __restrict__ Kh,
    const _Float16* __restrict__ Wqh, const _Float16* __restrict__ Wkh,
    const _Float16* __restrict__ Wvh,
    const float* __restrict__ bq, const float* __restrict__ bk,
    const float* __restrict__ bv,
    _Float16* __restrict__ qo, _Float16* __restrict__ ko,
    _Float16* __restrict__ vT) {
    const int z = blockIdx.z;
    const _Float16* A = (z == 0) ? Qh : Kh;
    const _Float16* W = (z == 0) ? Wqh : (z == 1 ? Wkh : Wvh);
    const float* bias = (z == 0) ? bq : (z == 1 ? bk : bv);

    __shared__ __align__(16) _Float16 At[128 * 32];
    __shared__ __align__(16) _Float16 Bt[128 * 32];

    const int tid = threadIdx.x;
    const int w = tid >> 6, lane = tid & 63;
    const int g = lane >> 4, c = lane & 15;
    const int m0 = blockIdx.x * 128, n0 = blockIdx.y * 128;
    const int wm = (w & 1) * 64, wn = (w >> 1) * 64;
    const int srow = w * 32 + (lane >> 2);
    const int scol = (lane & 3) * 8;  // in halves

    f32x4 acc[4][4] = {};

    for (int k0 = 0; k0 < 1024; k0 += 32) {
        __syncthreads();
#pragma unroll
        for (int t = 0; t < 2; ++t) {
            int r = srow + t * 16;
            gl_lds16(A + (size_t)(m0 + r) * 1024 + k0 + scol, &At[(w * 2 + t) * 512]);
            gl_lds16(W + (size_t)(n0 + r) * 1024 + k0 + scol, &Bt[(w * 2 + t) * 512]);
        }
        __syncthreads();
        f16x8 af[4], bf[4];
#pragma unroll
        for (int mt = 0; mt < 4; ++mt) af[mt] = *(const f16x8*)&At[(wm + mt * 16 + c) * 32 + g * 8];
#pragma unroll
        for (int nt = 0; nt < 4; ++nt) bf[nt] = *(const f16x8*)&Bt[(wn + nt * 16 + c) * 32 + g * 8];
#pragma unroll
        for (int mt = 0; mt < 4; ++mt)
#pragma unroll
            for (int nt = 0; nt < 4; ++nt)
                acc[mt][nt] = MFMA16(af[mt], bf[nt], acc[mt][nt]);
    }

    if (z != 2) {
        _Float16* C = (z == 0) ? qo : ko;
#pragma unroll
        for (int mt = 0; mt < 4; ++mt)
#pragma unroll
            for (int nt = 0; nt < 4; ++nt) {
                int col = n0 + wn + nt * 16 + c;
                float bb = bias[col];
#pragma unroll
                for (int i = 0; i < 4; ++i) {
                    int row = m0 + wm + mt * 16 + g * 4 + i;
                    C[(size_t)row * 1024 + col] = (_Float16)(acc[mt][nt][i] + bb);
                }
            }
    } else {
#pragma unroll
        for (int mt = 0; mt < 4; ++mt)
#pragma unroll
            for (int nt = 0; nt < 4; ++nt) {
                int col = n0 + wn + nt * 16 + c;
                int hh = col >> 6, dd = col & 63;
                float bb = bias[col];
                int row0 = m0 + wm + mt * 16 + g * 4;
                int bbi = row0 >> 10, nn = row0 & 1023;
                f16x4 pk;
#pragma unroll
                for (int i = 0; i < 4; ++i) pk[i] = (_Float16)(acc[mt][nt][i] + bb);
                *(f16x4*)&vT[((size_t)(bbi * 16 + hh) * 64 + dd) * 1024 + nn] = pk;
            }
    }
}

// ---------------------------------------------------------------------------
// fused attention v4: 1024 threads (16 waves), 32x32x16 MFMA, in-register P.
// Changes vs v3 (which spilled: 64 VGPR + 64 AGPR cap, VALU state > 64):
//  - PV runs on UNNORMALIZED e = exp2(s - pm_local); per-row scale sc applied
//    after PV via tiny per-wave sc_lds (own-wave, no barrier). PV MFMA no
//    longer depends on the cross-wave fixup -> fixup hides under PV.
//  - s[2] (32 regs) freed at pack time: exchanged av fragments (row = q5)
//    serve both MFMA and avg accumulation (k = kt*32+ks*16+8*hi+j).
//  - PV in two d-halves -> one f32x16 o accumulator (16 AGPR, not 32).
//  - O reduce+store of pair p-1 pipelined into QK(p) load shadow; barrier D
//    dropped (barrier A orders reduce-reads vs next Obuf writes). 2 bar/pair.
// ---------------------------------------------------------------------------
__global__ __launch_bounds__(1024, 4) void attn(
    const _Float16* __restrict__ qh, const _Float16* __restrict__ kh,
    const _Float16* __restrict__ vT, float* __restrict__ O,
    float* __restrict__ Aavg) {
    extern __shared__ __align__(16) char smem[];
    float* Obuf = (float*)smem;                 // [16][2112] f32 = 135168 B
    float* red_m = (float*)(smem + 135168);     // [16][32]
    float* red_l = red_m + 512;                 // [16][32]
    float* sc_lds = red_l + 512;                // [16][32]

    const int tid = threadIdx.x, w = tid >> 6, lane = tid & 63;
    const int q5 = lane & 31, hi = lane >> 5;

    // XCD-aware remap: group = f & 7 (one (chunk,b2) group per XCD)
    const int f = blockIdx.x + 32 * (blockIdx.y + 2 * blockIdx.z);
    const int grp = f & 7, q0 = (f >> 3) * 32;
    const int chunk = grp & 1, b2 = grp >> 1;

    float avg[2][2][8] = {};  // [kt][ks][j]: q=q5, k = w*64 + kt*32 + ks*16 + 8*hi + j

#pragma unroll 1
    for (int p = 0; p < 8; ++p) {
        const int m = b2 * 16 + chunk * 8 + p;
        const int b = m & 3, h = m >> 2;
        const _Float16* qb = qh + (size_t)b * 1048576 + h * 64;
        const _Float16* kb = kh + (size_t)b * 1048576 + h * 64;
        const _Float16* vb = vT + (size_t)(b * 16 + h) * 65536;

        // ---- issue QK global loads (latency hidden by pipelined reduce) ----
        f16x8 qf[4], kf[2][4];
#pragma unroll
        for (int dc = 0; dc < 4; ++dc)
            qf[dc] = *(const f16x8*)(qb + (size_t)(q0 + q5) * 1024 + dc * 16 + hi * 8);
#pragma unroll
        for (int kt = 0; kt < 2; ++kt) {
            const _Float16* kr = kb + (size_t)(w * 64 + kt * 32 + q5) * 1024 + hi * 8;
#pragma unroll
            for (int dc = 0; dc < 4; ++dc) kf[kt][dc] = *(const f16x8*)(kr + dc * 16);
        }

        // ---- pipelined: reduce + store O of pair p-1 ----
        if (p) {
            int mp = m - 1; int bp = mp & 3, hp = mp >> 2;
            int qq = tid >> 5, dd = (tid & 31) * 2;
            float sx = 0.f, sy = 0.f;
#pragma unroll
            for (int buf = 0; buf < 16; ++buf) {
                float2 v = *(float2*)&Obuf[buf * 2112 + qq * 66 + dd];
                sx += v.x; sy += v.y;
            }
            float2 r2; r2.x = sx; r2.y = sy;
            *(float2*)(O + (size_t)bp * 1048576 + (size_t)(q0 + qq) * 1024 + hp * 64 + dd) = r2;
        }

        // ---- QK^T: S^T tiles (row = k_local, col = q5) ----
        f32x16 s0 = {}, s1 = {};
#pragma unroll
        for (int dc = 0; dc < 4; ++dc) {
            s0 = MFMA32(kf[0][dc], qf[dc], s0);
            s1 = MFMA32(kf[1][dc], qf[dc], s1);
        }

        // ---- local (wave) max + exp + sum ----
        float pm = -3.0e38f;
#pragma unroll
        for (int r = 0; r < 16; ++r) { pm = fmaxf(pm, s0[r]); pm = fmaxf(pm, s1[r]); }
        pm = fmaxf(pm, __shfl_xor(pm, 32, 64));
        float l = 0.f;
#pragma unroll
        for (int r = 0; r < 16; ++r) {
            float e0 = exp2f((s0[r] - pm) * C1);
            float e1 = exp2f((s1[r] - pm) * C1);
            s0[r] = e0; s1[r] = e1; l += e0 + e1;
        }
        l += __shfl_xor(l, 32, 64);
        if (hi == 0) { red_m[w * 32 + q5] = pm; red_l[w * 32 + q5] = l; }
        __syncthreads();  // A

        // ---- pack e -> f16 pairs, half-wave exchange -> av (A-operand layout)
        u32x4 av[2][2];
#pragma unroll
        for (int kt = 0; kt < 2; ++kt) {
            unsigned pw[8];
#pragma unroll
            for (int r2 = 0; r2 < 8; ++r2) {
                float e0 = kt ? s1[2 * r2] : s0[2 * r2];
                float e1 = kt ? s1[2 * r2 + 1] : s0[2 * r2 + 1];
                f16x2 t2; t2[0] = (_Float16)e0; t2[1] = (_Float16)e1;
                pw[r2] = __builtin_bit_cast(unsigned, t2);
            }
            unsigned recv[2][2];
#pragma unroll
            for (int ks = 0; ks < 2; ++ks)
#pragma unroll
                for (int d = 0; d < 2; ++d) {
                    unsigned send = hi ? pw[4 * ks + d] : pw[4 * ks + 2 + d];
                    recv[ks][d] = (unsigned)__shfl_xor((int)send, 32, 64);
                }
#pragma unroll
            for (int ks = 0; ks < 2; ++ks) {
                unsigned own0 = hi ? pw[4 * ks + 2] : pw[4 * ks + 0];
                unsigned own1 = hi ? pw[4 * ks + 3] : pw[4 * ks + 1];
                u32x4 a;
                a[0] = hi ? recv[ks][0] : own0;   // j0,j1 (hi_src=0)
                a[1] = hi ? recv[ks][1] : own1;   // j2,j3
                a[2] = hi ? own0 : recv[ks][0];   // j4,j5 (hi_src=1)
                a[3] = hi ? own1 : recv[ks][1];   // j6,j7
                av[kt][ks] = a;
            }
        }

        // ---- global fixup (VALU+LDS, overlaps PV MFMA issue below) ----
        float mr[8], lr[8], M = -3.0e38f;
#pragma unroll
        for (int t = 0; t < 8; ++t) {
            mr[t] = red_m[(hi * 8 + t) * 32 + q5];
            lr[t] = red_l[(hi * 8 + t) * 32 + q5];
            M = fmaxf(M, mr[t]);
        }
        M = fmaxf(M, __shfl_xor(M, 32, 64));
        float L = 0.f;
#pragma unroll
        for (int t = 0; t < 8; ++t) L += lr[t] * exp2f((mr[t] - M) * C1);
        L += __shfl_xor(L, 32, 64);
        const float sc = exp2f((pm - M) * C1) / L;
        if (hi == 0) sc_lds[w * 32 + q5] = sc;

        // ---- PV (unnormalized), two d-halves; scale rows by sc on Obuf write
#pragma unroll
        for (int dh = 0; dh < 2; ++dh) {
            f32x16 o = {};
#pragma unroll
            for (int kt = 0; kt < 2; ++kt)
#pragma unroll
                for (int ks = 0; ks < 2; ++ks) {
                    f16x8 pa = __builtin_bit_cast(f16x8, av[kt][ks]);
                    const _Float16* vp = vb + (size_t)(dh * 32 + q5) * 1024 +
                                         w * 64 + kt * 32 + ks * 16 + hi * 8;
                    f16x8 vf = *(const f16x8*)vp;
                    o = MFMA32(pa, vf, o);
                }
            if (dh == 0) { asm volatile("s_waitcnt lgkmcnt(0)" ::: "memory"); }
            float* ob = Obuf + w * 2112 + dh * 32 + q5;
#pragma unroll
            for (int rg = 0; rg < 4; ++rg) {
                f32x4 sv = *(f32x4*)&sc_lds[w * 32 + rg * 8 + hi * 4];
#pragma unroll
                for (int r3 = 0; r3 < 4; ++r3) {
                    int qq = r3 + 8 * rg + 4 * hi;
                    ob[qq * 66] = o[rg * 4 + r3] * sv[r3];
                }
            }
        }

        // ---- avg accumulation from packed e (row = q5 -> own-lane sc) ----
#pragma unroll
        for (int kt = 0; kt < 2; ++kt)
#pragma unroll
            for (int ks = 0; ks < 2; ++ks) {
                f16x8 ev = __builtin_bit_cast(f16x8, av[kt][ks]);
#pragma unroll
                for (int j = 0; j < 8; ++j)
                    avg[kt][ks][j] += (float)ev[j] * sc;
            }
        __syncthreads();  // C
    }

    // ---- final reduce + store O for pair 7 ----
    {
        int mp = b2 * 16 + chunk * 8 + 7; int bp = mp & 3, hp = mp >> 2;
        int qq = tid >> 5, dd = (tid & 31) * 2;
        float sx = 0.f, sy = 0.f;
#pragma unroll
        for (int buf = 0; buf < 16; ++buf) {
            float2 v = *(float2*)&Obuf[buf * 2112 + qq * 66 + dd];
            sx += v.x; sy += v.y;
        }
        float2 r2; r2.x = sx; r2.y = sy;
        *(float2*)(O + (size_t)bp * 1048576 + (size_t)(q0 + qq) * 1024 + hp * 64 + dd) = r2;
    }
    __syncthreads();  // protect Obuf before avg staging

    // ---- A_avg: stage per-wave into LDS (stride 65), coalesced atomics ----
    {
        float* ab = Obuf + w * 2112;
#pragma unroll
        for (int kt = 0; kt < 2; ++kt)
#pragma unroll
            for (int ks = 0; ks < 2; ++ks)
#pragma unroll
                for (int j = 0; j < 8; ++j)
                    ab[q5 * 65 + kt * 32 + ks * 16 + hi * 8 + j] = avg[kt][ks][j];
        asm volatile("s_waitcnt lgkmcnt(0)" ::: "memory");
        float* Ab = Aavg + (size_t)b2 * 1048576 + (size_t)q0 * 1024 + w * 64;
#pragma unroll
        for (int i = 0; i < 32; ++i) {
            float v = ab[i * 65 + lane];
            __hip_atomic_fetch_add(&Ab[(size_t)i * 1024 + lane], v * 0.0625f,
                                   __ATOMIC_RELAXED, __HIP_MEMORY_SCOPE_AGENT);
        }
    }
}

// ---------------------------------------------------------------------------
extern "C" void kernel_launch(void* const* d_in, const int* in_sizes, int n_in,
                              void* d_out, int out_size, void* d_ws, size_t ws_size,
                              hipStream_t stream) {
    if (ws_size < ((size_t)46 << 20)) return;  // need 46 MB scratch

    const float* Q  = (const float*)d_in[0];
    const float* K  = (const float*)d_in[1];
    const float* Wq = (const float*)d_in[2];
    const float* bq = (const float*)d_in[3];
    const float* Wk = (const float*)d_in[4];
    const float* bk = (const float*)d_in[5];
    const float* Wv = (const float*)d_in[6];
    const float* bv = (const float*)d_in[7];

    char* ws = (char*)d_ws;
    _Float16* Qh  = (_Float16*)(ws);                      //  8 MB
    _Float16* Kh  = (_Float16*)(ws + ((size_t)8 << 20));  //  8 MB
    _Float16* Wqh = (_Float16*)(ws + ((size_t)16 << 20)); //  2 MB
    _Float16* Wkh = (_Float16*)(ws + ((size_t)18 << 20)); //  2 MB
    _Float16* Wvh = (_Float16*)(ws + ((size_t)20 << 20)); //  2 MB
    _Float16* qo  = (_Float16*)(ws + ((size_t)22 << 20)); //  8 MB
    _Float16* ko  = (_Float16*)(ws + ((size_t)30 << 20)); //  8 MB
    _Float16* vT  = (_Float16*)(ws + ((size_t)38 << 20)); //  8 MB

    float* O = (float*)d_out;
    float* Aavg = O + (size_t)4 * 1024 * 1024;

    // 1) convert inputs to fp16 (dst region is contiguous: Qh..Wvh)
    cvt_all<<<dim3(1441792 / 256), 256, 0, stream>>>(Q, K, Wq, Wk, Wv, Qh);

    // 2) three projection GEMMs in one launch (z selects)
    proj_gemm<<<dim3(32, 8, 3), 256, 0, stream>>>(Qh, Kh, Wqh, Wkh, Wvh,
                                                  bq, bk, bv, qo, ko, vT);

    // 3) zero A_avg output region (2 atomic contributions land on it)
    hipMemsetAsync(Aavg, 0, (size_t)4 * 1024 * 1024 * sizeof(float), stream);

    // 4) fused attention
    const int SMEM = 135168 + 3 * 2048;  // 141312 B
    hipFuncSetAttribute((const void*)attn, hipFuncAttributeMaxDynamicSharedMemorySize, SMEM);
    attn<<<dim3(32, 2, 4), 1024, SMEM, stream>>>(qo, ko, vT, O, Aavg);
}

// Round 5
// 165.515 us; speedup vs baseline: 1.1300x; 1.1300x over previous
//
#include <hip/hip_runtime.h>
#include <hip/hip_bf16.h>
#include <hip/hip_fp16.h>

typedef _Float16 f16x8 __attribute__((ext_vector_type(8)));
typedef _Float16 f16x4 __attribute__((ext_vector_type(4)));
typedef _Float16 f16x2 __attribute__((ext_vector_type(2)));
typedef float f32x4 __attribute__((ext_vector_type(4)));
typedef float f32x16 __attribute__((ext_vector_type(16)));
typedef unsigned int u32x4 __attribute__((ext_vector_type(4)));

#define MFMA16(a, b, c) __builtin_amdgcn_mfma_f32_16x16x32_f16(a, b, c, 0, 0, 0)
#define MFMA32(a, b, c) __builtin_amdgcn_mfma_f32_32x32x16_f16(a, b, c, 0, 0, 0)

// log2(e) / sqrt(1024)
#define C1 0.045084220027780106f

// ---------------------------------------------------------------------------
// convert f32 -> fp16 for Q, K, Wq, Wk, Wv into one contiguous ws region
// ---------------------------------------------------------------------------
__global__ void cvt_all(const float* __restrict__ Q, const float* __restrict__ K,
                        const float* __restrict__ Wq, const float* __restrict__ Wk,
                        const float* __restrict__ Wv, _Float16* __restrict__ dst) {
    int i = blockIdx.x * blockDim.x + threadIdx.x;  // i indexes groups of 8 f32
    const float* s;
    int off;
    if (i < 524288)       { s = Q;  off = 0;       }
    else if (i < 1048576) { s = K;  off = 524288;  }
    else if (i < 1179648) { s = Wq; off = 1048576; }
    else if (i < 1310720) { s = Wk; off = 1179648; }
    else                  { s = Wv; off = 1310720; }
    int j = i - off;
    float4 a = ((const float4*)s)[2 * j];
    float4 b = ((const float4*)s)[2 * j + 1];
    f16x8 h;
    h[0] = (_Float16)a.x; h[1] = (_Float16)a.y; h[2] = (_Float16)a.z; h[3] = (_Float16)a.w;
    h[4] = (_Float16)b.x; h[5] = (_Float16)b.y; h[6] = (_Float16)b.z; h[7] = (_Float16)b.w;
    ((f16x8*)dst)[i] = h;
}

// ---------------------------------------------------------------------------
// projection GEMM (unchanged): C[m,n] = A[m,:]·W[n,:] + bias[n]
// z=0: q, z=1: k, z=2: v written transposed as vT[b][h][d][n]
// ---------------------------------------------------------------------------
__device__ __forceinline__ void gl_lds16(const void* g, void* l) {
    __builtin_amdgcn_global_load_lds(
        (const __attribute__((address_space(1))) void*)g,
        (__attribute__((address_space(3))) void*)l, 16, 0, 0);
}

__global__ __launch_bounds__(256) void proj_gemm(
    const _Float16* __restrict__ Qh, const _Float16* __restrict__ Kh,
    const _Float16* __restrict__ Wqh, const _Float16* __restrict__ Wkh,
    const _Float16* __restrict__ Wvh,
    const float* __restrict__ bq, const float* __restrict__ bk,
    const float* __restrict__ bv,
    _Float16* __restrict__ qo, _Float16* __restrict__ ko,
    _Float16* __restrict__ vT) {
    const int z = blockIdx.z;
    const _Float16* A = (z == 0) ? Qh : Kh;
    const _Float16* W = (z == 0) ? Wqh : (z == 1 ? Wkh : Wvh);
    const float* bias = (z == 0) ? bq : (z == 1 ? bk : bv);

    __shared__ __align__(16) _Float16 At[128 * 32];
    __shared__ __align__(16) _Float16 Bt[128 * 32];

    const int tid = threadIdx.x;
    const int w = tid >> 6, lane = tid & 63;
    const int g = lane >> 4, c = lane & 15;
    const int m0 = blockIdx.x * 128, n0 = blockIdx.y * 128;
    const int wm = (w & 1) * 64, wn = (w >> 1) * 64;
    const int srow = w * 32 + (lane >> 2);
    const int scol = (lane & 3) * 8;  // in halves

    f32x4 acc[4][4] = {};

    for (int k0 = 0; k0 < 1024; k0 += 32) {
        __syncthreads();
#pragma unroll
        for (int t = 0; t < 2; ++t) {
            int r = srow + t * 16;
            gl_lds16(A + (size_t)(m0 + r) * 1024 + k0 + scol, &At[(w * 2 + t) * 512]);
            gl_lds16(W + (size_t)(n0 + r) * 1024 + k0 + scol, &Bt[(w * 2 + t) * 512]);
        }
        __syncthreads();
        f16x8 af[4], bf[4];
#pragma unroll
        for (int mt = 0; mt < 4; ++mt) af[mt] = *(const f16x8*)&At[(wm + mt * 16 + c) * 32 + g * 8];
#pragma unroll
        for (int nt = 0; nt < 4; ++nt) bf[nt] = *(const f16x8*)&Bt[(wn + nt * 16 + c) * 32 + g * 8];
#pragma unroll
        for (int mt = 0; mt < 4; ++mt)
#pragma unroll
            for (int nt = 0; nt < 4; ++nt)
                acc[mt][nt] = MFMA16(af[mt], bf[nt], acc[mt][nt]);
    }

    if (z != 2) {
        _Float16* C = (z == 0) ? qo : ko;
#pragma unroll
        for (int mt = 0; mt < 4; ++mt)
#pragma unroll
            for (int nt = 0; nt < 4; ++nt) {
                int col = n0 + wn + nt * 16 + c;
                float bb = bias[col];
#pragma unroll
                for (int i = 0; i < 4; ++i) {
                    int row = m0 + wm + mt * 16 + g * 4 + i;
                    C[(size_t)row * 1024 + col] = (_Float16)(acc[mt][nt][i] + bb);
                }
            }
    } else {
#pragma unroll
        for (int mt = 0; mt < 4; ++mt)
#pragma unroll
            for (int nt = 0; nt < 4; ++nt) {
                int col = n0 + wn + nt * 16 + c;
                int hh = col >> 6, dd = col & 63;
                float bb = bias[col];
                int row0 = m0 + wm + mt * 16 + g * 4;
                int bbi = row0 >> 10, nn = row0 & 1023;
                f16x4 pk;
#pragma unroll
                for (int i = 0; i < 4; ++i) pk[i] = (_Float16)(acc[mt][nt][i] + bb);
                *(f16x4*)&vT[((size_t)(bbi * 16 + hh) * 64 + dd) * 1024 + nn] = pk;
            }
    }
}

// ---------------------------------------------------------------------------
// fused attention v5: 512 threads (8 waves), launch_bounds(512,2) -> 256
// regs/thread (the v3/v4 1024-thread shape was hard-capped at 128 and
// spilled). Wave w owns k in [w*128, w*128+128): 4 S-tiles of 32k.
// Same validated fragment maps: swapped QK^T (q=lane&31), pack+half-wave
// exchange -> PV A-frag, PV on unnormalized e with post-scale, avg in regs.
// 8-wave barriers (2/pair), Obuf partials 8x(32x68) f32 (aligned f32x4
// reduce), A_avg staged at stride 129 then coalesced atomics.
// ---------------------------------------------------------------------------
__global__ __launch_bounds__(512, 2) void attn(
    const _Float16* __restrict__ qh, const _Float16* __restrict__ kh,
    const _Float16* __restrict__ vT, float* __restrict__ O,
    float* __restrict__ Aavg) {
    extern __shared__ __align__(16) char smem[];
    float* Obuf = (float*)smem;                 // [8][32][68] f32 = 69632 B
    float* red_m = (float*)(smem + 69632);      // [8][32]
    float* red_l = red_m + 256;                 // [8][32]
    float* sc_lds = red_l + 256;                // [8][32]

    const int tid = threadIdx.x, w = tid >> 6, lane = tid & 63;
    const int q5 = lane & 31, hi = lane >> 5;

    // XCD-aware remap: group = f & 7 (one (chunk,b2) group per XCD)
    const int f = blockIdx.x;
    const int grp = f & 7, q0 = (f >> 3) * 32;
    const int chunk = grp & 1, b2 = grp >> 1;

    // q = q5, k = w*128 + kt*32 + ks*16 + 8*hi + j
    float avg[4][2][8] = {};

#pragma unroll 1
    for (int p = 0; p < 8; ++p) {
        const int m = b2 * 16 + chunk * 8 + p;
        const int b = m & 3, h = m >> 2;
        const _Float16* qb = qh + (size_t)b * 1048576 + h * 64;
        const _Float16* kb = kh + (size_t)b * 1048576 + h * 64;
        const _Float16* vb = vT + (size_t)(b * 16 + h) * 65536;

        // ---- issue Q/K global loads ----
        f16x8 qf[4], kf[4][4];
#pragma unroll
        for (int dc = 0; dc < 4; ++dc)
            qf[dc] = *(const f16x8*)(qb + (size_t)(q0 + q5) * 1024 + dc * 16 + hi * 8);
#pragma unroll
        for (int kt = 0; kt < 4; ++kt) {
            const _Float16* kr = kb + (size_t)(w * 128 + kt * 32 + q5) * 1024 + hi * 8;
#pragma unroll
            for (int dc = 0; dc < 4; ++dc) kf[kt][dc] = *(const f16x8*)(kr + dc * 16);
        }

        // ---- pipelined: reduce + store O of pair p-1 (LDS, overlaps loads) ----
        if (p) {
            int mp = m - 1; int bp = mp & 3, hp = mp >> 2;
            int qq = tid >> 4, dd = (tid & 15) * 4;
            f32x4 acc = {};
#pragma unroll
            for (int buf = 0; buf < 8; ++buf) {
                f32x4 v = *(f32x4*)&Obuf[buf * 2176 + qq * 68 + dd];
                acc += v;
            }
            *(f32x4*)(O + (size_t)bp * 1048576 + (size_t)(q0 + qq) * 1024 + hp * 64 + dd) = acc;
        }

        // ---- QK^T: S^T tiles (row = k_local, col = q5) ----
        f32x16 s[4] = {};
#pragma unroll
        for (int kt = 0; kt < 4; ++kt)
#pragma unroll
            for (int dc = 0; dc < 4; ++dc)
                s[kt] = MFMA32(kf[kt][dc], qf[dc], s[kt]);

        // ---- local (wave) max + exp + sum ----
        float pm = -3.0e38f;
#pragma unroll
        for (int kt = 0; kt < 4; ++kt)
#pragma unroll
            for (int r = 0; r < 16; ++r) pm = fmaxf(pm, s[kt][r]);
        pm = fmaxf(pm, __shfl_xor(pm, 32, 64));
        float l = 0.f;
#pragma unroll
        for (int kt = 0; kt < 4; ++kt)
#pragma unroll
            for (int r = 0; r < 16; ++r) {
                float e = exp2f((s[kt][r] - pm) * C1);
                s[kt][r] = e; l += e;
            }
        l += __shfl_xor(l, 32, 64);
        if (hi == 0) { red_m[w * 32 + q5] = pm; red_l[w * 32 + q5] = l; }
        __syncthreads();  // A

        // ---- pack e -> f16 pairs, half-wave exchange -> av (A-operand layout)
        u32x4 av[4][2];
#pragma unroll
        for (int kt = 0; kt < 4; ++kt) {
            unsigned pw[8];
#pragma unroll
            for (int r2 = 0; r2 < 8; ++r2) {
                f16x2 t2;
                t2[0] = (_Float16)s[kt][2 * r2];
                t2[1] = (_Float16)s[kt][2 * r2 + 1];
                pw[r2] = __builtin_bit_cast(unsigned, t2);
            }
            unsigned recv[2][2];
#pragma unroll
            for (int ks = 0; ks < 2; ++ks)
#pragma unroll
                for (int d = 0; d < 2; ++d) {
                    unsigned send = hi ? pw[4 * ks + d] : pw[4 * ks + 2 + d];
                    recv[ks][d] = (unsigned)__shfl_xor((int)send, 32, 64);
                }
#pragma unroll
            for (int ks = 0; ks < 2; ++ks) {
                unsigned own0 = hi ? pw[4 * ks + 2] : pw[4 * ks + 0];
                unsigned own1 = hi ? pw[4 * ks + 3] : pw[4 * ks + 1];
                u32x4 a;
                a[0] = hi ? recv[ks][0] : own0;   // j0,j1 (hi_src=0)
                a[1] = hi ? recv[ks][1] : own1;   // j2,j3
                a[2] = hi ? own0 : recv[ks][0];   // j4,j5 (hi_src=1)
                a[3] = hi ? own1 : recv[ks][1];   // j6,j7
                av[kt][ks] = a;
            }
        }

        // ---- global fixup over 8 waves (hi-split 4+4, shfl combine) ----
        float mr[4], lr[4], M = -3.0e38f;
#pragma unroll
        for (int t = 0; t < 4; ++t) {
            int wv = hi * 4 + t;
            mr[t] = red_m[wv * 32 + q5];
            lr[t] = red_l[wv * 32 + q5];
            M = fmaxf(M, mr[t]);
        }
        M = fmaxf(M, __shfl_xor(M, 32, 64));
        float L = 0.f;
#pragma unroll
        for (int t = 0; t < 4; ++t) L += lr[t] * exp2f((mr[t] - M) * C1);
        L += __shfl_xor(L, 32, 64);
        const float sc = exp2f((pm - M) * C1) / L;
        if (hi == 0) sc_lds[w * 32 + q5] = sc;
        asm volatile("s_waitcnt lgkmcnt(0)" ::: "memory");

        // ---- PV (unnormalized), two d-halves; scale rows by sc on Obuf write
#pragma unroll
        for (int dh = 0; dh < 2; ++dh) {
            f32x16 o = {};
#pragma unroll
            for (int kt = 0; kt < 4; ++kt)
#pragma unroll
                for (int ks = 0; ks < 2; ++ks) {
                    f16x8 pa = __builtin_bit_cast(f16x8, av[kt][ks]);
                    const _Float16* vp = vb + (size_t)(dh * 32 + q5) * 1024 +
                                         w * 128 + kt * 32 + ks * 16 + hi * 8;
                    f16x8 vf = *(const f16x8*)vp;
                    o = MFMA32(pa, vf, o);
                }
            float* ob = Obuf + w * 2176 + dh * 32 + q5;
#pragma unroll
            for (int rg = 0; rg < 4; ++rg) {
                f32x4 sv = *(f32x4*)&sc_lds[w * 32 + rg * 8 + hi * 4];
#pragma unroll
                for (int r3 = 0; r3 < 4; ++r3) {
                    int qq = r3 + 8 * rg + 4 * hi;
                    ob[qq * 68] = o[rg * 4 + r3] * sv[r3];
                }
            }
        }

        // ---- avg accumulation from packed e (row = q5 -> own-lane sc) ----
#pragma unroll
        for (int kt = 0; kt < 4; ++kt)
#pragma unroll
            for (int ks = 0; ks < 2; ++ks) {
                f16x8 ev = __builtin_bit_cast(f16x8, av[kt][ks]);
#pragma unroll
                for (int j = 0; j < 8; ++j)
                    avg[kt][ks][j] += (float)ev[j] * sc;
            }
        __syncthreads();  // C
    }

    // ---- final reduce + store O for pair 7 ----
    {
        int mp = b2 * 16 + chunk * 8 + 7; int bp = mp & 3, hp = mp >> 2;
        int qq = tid >> 4, dd = (tid & 15) * 4;
        f32x4 acc = {};
#pragma unroll
        for (int buf = 0; buf < 8; ++buf) {
            f32x4 v = *(f32x4*)&Obuf[buf * 2176 + qq * 68 + dd];
            acc += v;
        }
        *(f32x4*)(O + (size_t)bp * 1048576 + (size_t)(q0 + qq) * 1024 + hp * 64 + dd) = acc;
    }
    __syncthreads();  // protect smem before avg staging

    // ---- A_avg: stage per-wave into LDS (stride 129), coalesced atomics ----
    {
        float* ab = (float*)smem + w * 4128;  // 32*129 floats per wave
#pragma unroll
        for (int kt = 0; kt < 4; ++kt)
#pragma unroll
            for (int ks = 0; ks < 2; ++ks)
#pragma unroll
                for (int j = 0; j < 8; ++j)
                    ab[q5 * 129 + kt * 32 + ks * 16 + hi * 8 + j] = avg[kt][ks][j];
        asm volatile("s_waitcnt lgkmcnt(0)" ::: "memory");
        float* Ab = Aavg + (size_t)b2 * 1048576 + (size_t)q0 * 1024 + w * 128;
#pragma unroll
        for (int i = 0; i < 32; ++i) {
            float v0 = ab[i * 129 + lane];
            float v1 = ab[i * 129 + 64 + lane];
            __hip_atomic_fetch_add(&Ab[(size_t)i * 1024 + lane], v0 * 0.0625f,
                                   __ATOMIC_RELAXED, __HIP_MEMORY_SCOPE_AGENT);
            __hip_atomic_fetch_add(&Ab[(size_t)i * 1024 + 64 + lane], v1 * 0.0625f,
                                   __ATOMIC_RELAXED, __HIP_MEMORY_SCOPE_AGENT);
        }
    }
}

// ---------------------------------------------------------------------------
extern "C" void kernel_launch(void* const* d_in, const int* in_sizes, int n_in,
                              void* d_out, int out_size, void* d_ws, size_t ws_size,
                              hipStream_t stream) {
    if (ws_size < ((size_t)46 << 20)) return;  // need 46 MB scratch

    const float* Q  = (const float*)d_in[0];
    const float* K  = (const float*)d_in[1];
    const float* Wq = (const float*)d_in[2];
    const float* bq = (const float*)d_in[3];
    const float* Wk = (const float*)d_in[4];
    const float* bk = (const float*)d_in[5];
    const float* Wv = (const float*)d_in[6];
    const float* bv = (const float*)d_in[7];

    char* ws = (char*)d_ws;
    _Float16* Qh  = (_Float16*)(ws);                      //  8 MB
    _Float16* Kh  = (_Float16*)(ws + ((size_t)8 << 20));  //  8 MB
    _Float16* Wqh = (_Float16*)(ws + ((size_t)16 << 20)); //  2 MB
    _Float16* Wkh = (_Float16*)(ws + ((size_t)18 << 20)); //  2 MB
    _Float16* Wvh = (_Float16*)(ws + ((size_t)20 << 20)); //  2 MB
    _Float16* qo  = (_Float16*)(ws + ((size_t)22 << 20)); //  8 MB
    _Float16* ko  = (_Float16*)(ws + ((size_t)30 << 20)); //  8 MB
    _Float16* vT  = (_Float16*)(ws + ((size_t)38 << 20)); //  8 MB

    float* O = (float*)d_out;
    float* Aavg = O + (size_t)4 * 1024 * 1024;

    // 1) convert inputs to fp16 (dst region is contiguous: Qh..Wvh)
    cvt_all<<<dim3(1441792 / 256), 256, 0, stream>>>(Q, K, Wq, Wk, Wv, Qh);

    // 2) three projection GEMMs in one launch (z selects)
    proj_gemm<<<dim3(32, 8, 3), 256, 0, stream>>>(Qh, Kh, Wqh, Wkh, Wvh,
                                                  bq, bk, bv, qo, ko, vT);

    // 3) zero A_avg output region (2 atomic contributions land on it)
    hipMemsetAsync(Aavg, 0, (size_t)4 * 1024 * 1024 * sizeof(float), stream);

    // 4) fused attention: 256 blocks x 512 threads, 132096 B LDS
    const int SMEM = 132096;
    hipFuncSetAttribute((const void*)attn, hipFuncAttributeMaxDynamicSharedMemorySize, SMEM);
    attn<<<dim3(256), 512, SMEM, stream>>>(qo, ko, vT, O, Aavg);
}

// Round 6
// 154.867 us; speedup vs baseline: 1.2077x; 1.0688x over previous
//
#include <hip/hip_runtime.h>
#include <hip/hip_bf16.h>
#include <hip/hip_fp16.h>

typedef _Float16 f16x8 __attribute__((ext_vector_type(8)));
typedef _Float16 f16x4 __attribute__((ext_vector_type(4)));
typedef _Float16 f16x2 __attribute__((ext_vector_type(2)));
typedef float f32x4 __attribute__((ext_vector_type(4)));
typedef float f32x16 __attribute__((ext_vector_type(16)));
typedef unsigned int u32x4 __attribute__((ext_vector_type(4)));

#define MFMA16(a, b, c) __builtin_amdgcn_mfma_f32_16x16x32_f16(a, b, c, 0, 0, 0)
#define MFMA32(a, b, c) __builtin_amdgcn_mfma_f32_32x32x16_f16(a, b, c, 0, 0, 0)

// log2(e) / sqrt(1024)
#define C1 0.045084220027780106f

// ---------------------------------------------------------------------------
// convert f32 -> fp16 for Q, K, Wq, Wk, Wv into one contiguous ws region
// ---------------------------------------------------------------------------
__global__ void cvt_all(const float* __restrict__ Q, const float* __restrict__ K,
                        const float* __restrict__ Wq, const float* __restrict__ Wk,
                        const float* __restrict__ Wv, _Float16* __restrict__ dst) {
    int i = blockIdx.x * blockDim.x + threadIdx.x;  // i indexes groups of 8 f32
    const float* s;
    int off;
    if (i < 524288)       { s = Q;  off = 0;       }
    else if (i < 1048576) { s = K;  off = 524288;  }
    else if (i < 1179648) { s = Wq; off = 1048576; }
    else if (i < 1310720) { s = Wk; off = 1179648; }
    else                  { s = Wv; off = 1310720; }
    int j = i - off;
    float4 a = ((const float4*)s)[2 * j];
    float4 b = ((const float4*)s)[2 * j + 1];
    f16x8 h;
    h[0] = (_Float16)a.x; h[1] = (_Float16)a.y; h[2] = (_Float16)a.z; h[3] = (_Float16)a.w;
    h[4] = (_Float16)b.x; h[5] = (_Float16)b.y; h[6] = (_Float16)b.z; h[7] = (_Float16)b.w;
    ((f16x8*)dst)[i] = h;
}

// ---------------------------------------------------------------------------
// projection GEMM (unchanged): C[m,n] = A[m,:]·W[n,:] + bias[n]
// z=0: q, z=1: k, z=2: v written transposed as vT[b][h][d][n]
// ---------------------------------------------------------------------------
__device__ __forceinline__ void gl_lds16(const void* g, void* l) {
    __builtin_amdgcn_global_load_lds(
        (const __attribute__((address_space(1))) void*)g,
        (__attribute__((address_space(3))) void*)l, 16, 0, 0);
}

__global__ __launch_bounds__(256) void proj_gemm(
    const _Float16* __restrict__ Qh, const _Float16* __restrict__ Kh,
    const _Float16* __restrict__ Wqh, const _Float16* __restrict__ Wkh,
    const _Float16* __restrict__ Wvh,
    const float* __restrict__ bq, const float* __restrict__ bk,
    const float* __restrict__ bv,
    _Float16* __restrict__ qo, _Float16* __restrict__ ko,
    _Float16* __restrict__ vT) {
    const int z = blockIdx.z;
    const _Float16* A = (z == 0) ? Qh : Kh;
    const _Float16* W = (z == 0) ? Wqh : (z == 1 ? Wkh : Wvh);
    const float* bias = (z == 0) ? bq : (z == 1 ? bk : bv);

    __shared__ __align__(16) _Float16 At[128 * 32];
    __shared__ __align__(16) _Float16 Bt[128 * 32];

    const int tid = threadIdx.x;
    const int w = tid >> 6, lane = tid & 63;
    const int g = lane >> 4, c = lane & 15;
    const int m0 = blockIdx.x * 128, n0 = blockIdx.y * 128;
    const int wm = (w & 1) * 64, wn = (w >> 1) * 64;
    const int srow = w * 32 + (lane >> 2);
    const int scol = (lane & 3) * 8;  // in halves

    f32x4 acc[4][4] = {};

    for (int k0 = 0; k0 < 1024; k0 += 32) {
        __syncthreads();
#pragma unroll
        for (int t = 0; t < 2; ++t) {
            int r = srow + t * 16;
            gl_lds16(A + (size_t)(m0 + r) * 1024 + k0 + scol, &At[(w * 2 + t) * 512]);
            gl_lds16(W + (size_t)(n0 + r) * 1024 + k0 + scol, &Bt[(w * 2 + t) * 512]);
        }
        __syncthreads();
        f16x8 af[4], bf[4];
#pragma unroll
        for (int mt = 0; mt < 4; ++mt) af[mt] = *(const f16x8*)&At[(wm + mt * 16 + c) * 32 + g * 8];
#pragma unroll
        for (int nt = 0; nt < 4; ++nt) bf[nt] = *(const f16x8*)&Bt[(wn + nt * 16 + c) * 32 + g * 8];
#pragma unroll
        for (int mt = 0; mt < 4; ++mt)
#pragma unroll
            for (int nt = 0; nt < 4; ++nt)
                acc[mt][nt] = MFMA16(af[mt], bf[nt], acc[mt][nt]);
    }

    if (z != 2) {
        _Float16* C = (z == 0) ? qo : ko;
#pragma unroll
        for (int mt = 0; mt < 4; ++mt)
#pragma unroll
            for (int nt = 0; nt < 4; ++nt) {
                int col = n0 + wn + nt * 16 + c;
                float bb = bias[col];
#pragma unroll
                for (int i = 0; i < 4; ++i) {
                    int row = m0 + wm + mt * 16 + g * 4 + i;
                    C[(size_t)row * 1024 + col] = (_Float16)(acc[mt][nt][i] + bb);
                }
            }
    } else {
#pragma unroll
        for (int mt = 0; mt < 4; ++mt)
#pragma unroll
            for (int nt = 0; nt < 4; ++nt) {
                int col = n0 + wn + nt * 16 + c;
                int hh = col >> 6, dd = col & 63;
                float bb = bias[col];
                int row0 = m0 + wm + mt * 16 + g * 4;
                int bbi = row0 >> 10, nn = row0 & 1023;
                f16x4 pk;
#pragma unroll
                for (int i = 0; i < 4; ++i) pk[i] = (_Float16)(acc[mt][nt][i] + bb);
                *(f16x4*)&vT[((size_t)(bbi * 16 + hh) * 64 + dd) * 1024 + nn] = pk;
            }
    }
}

// ---------------------------------------------------------------------------
// fused attention v6: 512 threads (8 waves), 32x32x16 MFMA, in-register P.
// vs v5:
//  - sc folded into the P pack (sc is per-lane in A-layout) -> PV output is
//    final; sc_lds and O post-scale deleted.
//  - A_avg accumulated by MFMA: acc_avg[kt] += av[kt][ks] x Bsel[ks], where
//    Bsel0=[I16|0], Bsel1=[0|I16] selector B-fragments. Deletes the per-pair
//    avg VALU loop and the LDS staging tail.
//  - NO ATOMICS: each (chunk) writes its own f16 partial buffer
//    part[b2][q][k] (exactly one writer per element); add_avg sums the two
//    partials deterministically. (Theory: 8.4M device-scope f32 atomics were
//    a ~60+ us serialized tail in v1-v5.)
// ---------------------------------------------------------------------------
__global__ __launch_bounds__(512, 2) void attn(
    const _Float16* __restrict__ qh, const _Float16* __restrict__ kh,
    const _Float16* __restrict__ vT, float* __restrict__ O,
    _Float16* __restrict__ part0, _Float16* __restrict__ part1) {
    extern __shared__ __align__(16) char smem[];
    float* Obuf = (float*)smem;                 // [8][32][68] f32 = 69632 B
    float* red_m = (float*)(smem + 69632);      // [8][32]
    float* red_l = red_m + 256;                 // [8][32]

    const int tid = threadIdx.x, w = tid >> 6, lane = tid & 63;
    const int q5 = lane & 31, hi = lane >> 5;

    // XCD-aware remap: group = f & 7 (one (chunk,b2) group per XCD)
    const int f = blockIdx.x;
    const int grp = f & 7, q0 = (f >> 3) * 32;
    const int chunk = grp & 1, b2 = grp >> 1;

    // Bsel B-fragments: Bsel[ks](k,n) = (k == n&15 && n>>4 == ks)
    // B layout: lane n = q5 (col), k = hi*8 + j
    f16x8 bsel[2];
#pragma unroll
    for (int ks = 0; ks < 2; ++ks)
#pragma unroll
        for (int j = 0; j < 8; ++j)
            bsel[ks][j] = (hi * 8 + j == (q5 & 15) && (q5 >> 4) == ks)
                              ? (_Float16)1.0f : (_Float16)0.0f;

    // acc_avg[kt]: D layout, q = (r&3)+8*(r>>2)+4*hi, k = w*128 + kt*32 + q5
    f32x16 aacc[4] = {};

#pragma unroll 1
    for (int p = 0; p < 8; ++p) {
        const int m = b2 * 16 + chunk * 8 + p;
        const int b = m & 3, h = m >> 2;
        const _Float16* qb = qh + (size_t)b * 1048576 + h * 64;
        const _Float16* kb = kh + (size_t)b * 1048576 + h * 64;
        const _Float16* vb = vT + (size_t)(b * 16 + h) * 65536;

        // ---- issue Q/K global loads ----
        f16x8 qf[4], kf[4][4];
#pragma unroll
        for (int dc = 0; dc < 4; ++dc)
            qf[dc] = *(const f16x8*)(qb + (size_t)(q0 + q5) * 1024 + dc * 16 + hi * 8);
#pragma unroll
        for (int kt = 0; kt < 4; ++kt) {
            const _Float16* kr = kb + (size_t)(w * 128 + kt * 32 + q5) * 1024 + hi * 8;
#pragma unroll
            for (int dc = 0; dc < 4; ++dc) kf[kt][dc] = *(const f16x8*)(kr + dc * 16);
        }

        // ---- pipelined: reduce + store O of pair p-1 (overlaps loads) ----
        if (p) {
            int mp = m - 1; int bp = mp & 3, hp = mp >> 2;
            int qq = tid >> 4, dd = (tid & 15) * 4;
            f32x4 acc = {};
#pragma unroll
            for (int buf = 0; buf < 8; ++buf) {
                f32x4 v = *(f32x4*)&Obuf[buf * 2176 + qq * 68 + dd];
                acc += v;
            }
            *(f32x4*)(O + (size_t)bp * 1048576 + (size_t)(q0 + qq) * 1024 + hp * 64 + dd) = acc;
        }

        // ---- QK^T: S^T tiles (row = k_local, col = q5) ----
        f32x16 s[4] = {};
#pragma unroll
        for (int kt = 0; kt < 4; ++kt)
#pragma unroll
            for (int dc = 0; dc < 4; ++dc)
                s[kt] = MFMA32(kf[kt][dc], qf[dc], s[kt]);

        // ---- local (wave) max + exp + sum ----
        float pm = -3.0e38f;
#pragma unroll
        for (int kt = 0; kt < 4; ++kt)
#pragma unroll
            for (int r = 0; r < 16; ++r) pm = fmaxf(pm, s[kt][r]);
        pm = fmaxf(pm, __shfl_xor(pm, 32, 64));
        float l = 0.f;
#pragma unroll
        for (int kt = 0; kt < 4; ++kt)
#pragma unroll
            for (int r = 0; r < 16; ++r) {
                float e = exp2f((s[kt][r] - pm) * C1);
                s[kt][r] = e; l += e;
            }
        l += __shfl_xor(l, 32, 64);
        if (hi == 0) { red_m[w * 32 + q5] = pm; red_l[w * 32 + q5] = l; }
        __syncthreads();  // A

        // ---- global fixup over 8 waves (hi-split 4+4, shfl combine) ----
        float mr[4], lr[4], M = -3.0e38f;
#pragma unroll
        for (int t = 0; t < 4; ++t) {
            int wv = hi * 4 + t;
            mr[t] = red_m[wv * 32 + q5];
            lr[t] = red_l[wv * 32 + q5];
            M = fmaxf(M, mr[t]);
        }
        M = fmaxf(M, __shfl_xor(M, 32, 64));
        float L = 0.f;
#pragma unroll
        for (int t = 0; t < 4; ++t) L += lr[t] * exp2f((mr[t] - M) * C1);
        L += __shfl_xor(L, 32, 64);
        const float sc = exp2f((pm - M) * C1) / L;

        // ---- pack P = e*sc -> f16 pairs, half-wave exchange -> av ----
        u32x4 av[4][2];
#pragma unroll
        for (int kt = 0; kt < 4; ++kt) {
            unsigned pw[8];
#pragma unroll
            for (int r2 = 0; r2 < 8; ++r2) {
                f16x2 t2;
                t2[0] = (_Float16)(s[kt][2 * r2] * sc);
                t2[1] = (_Float16)(s[kt][2 * r2 + 1] * sc);
                pw[r2] = __builtin_bit_cast(unsigned, t2);
            }
            unsigned recv[2][2];
#pragma unroll
            for (int ks = 0; ks < 2; ++ks)
#pragma unroll
                for (int d = 0; d < 2; ++d) {
                    unsigned send = hi ? pw[4 * ks + d] : pw[4 * ks + 2 + d];
                    recv[ks][d] = (unsigned)__shfl_xor((int)send, 32, 64);
                }
#pragma unroll
            for (int ks = 0; ks < 2; ++ks) {
                unsigned own0 = hi ? pw[4 * ks + 2] : pw[4 * ks + 0];
                unsigned own1 = hi ? pw[4 * ks + 3] : pw[4 * ks + 1];
                u32x4 a;
                a[0] = hi ? recv[ks][0] : own0;   // j0,j1 (hi_src=0)
                a[1] = hi ? recv[ks][1] : own1;   // j2,j3
                a[2] = hi ? own0 : recv[ks][0];   // j4,j5 (hi_src=1)
                a[3] = hi ? own1 : recv[ks][1];   // j6,j7
                av[kt][ks] = a;
            }
        }

        // ---- PV (normalized P), two d-halves; write Obuf directly ----
#pragma unroll
        for (int dh = 0; dh < 2; ++dh) {
            f32x16 o = {};
#pragma unroll
            for (int kt = 0; kt < 4; ++kt)
#pragma unroll
                for (int ks = 0; ks < 2; ++ks) {
                    f16x8 pa = __builtin_bit_cast(f16x8, av[kt][ks]);
                    const _Float16* vp = vb + (size_t)(dh * 32 + q5) * 1024 +
                                         w * 128 + kt * 32 + ks * 16 + hi * 8;
                    f16x8 vf = *(const f16x8*)vp;
                    o = MFMA32(pa, vf, o);
                }
            float* ob = Obuf + w * 2176 + dh * 32 + q5;
#pragma unroll
            for (int r = 0; r < 16; ++r) {
                int qq = (r & 3) + 8 * (r >> 2) + 4 * hi;
                ob[qq * 68] = o[r];
            }
        }

        // ---- A_avg accumulation by MFMA (P itself into aacc) ----
#pragma unroll
        for (int kt = 0; kt < 4; ++kt) {
            aacc[kt] = MFMA32(__builtin_bit_cast(f16x8, av[kt][0]), bsel[0], aacc[kt]);
            aacc[kt] = MFMA32(__builtin_bit_cast(f16x8, av[kt][1]), bsel[1], aacc[kt]);
        }
        __syncthreads();  // C
    }

    // ---- final reduce + store O for pair 7 ----
    {
        int mp = b2 * 16 + chunk * 8 + 7; int bp = mp & 3, hp = mp >> 2;
        int qq = tid >> 4, dd = (tid & 15) * 4;
        f32x4 acc = {};
#pragma unroll
        for (int buf = 0; buf < 8; ++buf) {
            f32x4 v = *(f32x4*)&Obuf[buf * 2176 + qq * 68 + dd];
            acc += v;
        }
        *(f32x4*)(O + (size_t)bp * 1048576 + (size_t)(q0 + qq) * 1024 + hp * 64 + dd) = acc;
    }

    // ---- A_avg tail: non-atomic f16 partial stores (one writer/element) ----
    {
        _Float16* pb = (chunk ? part1 : part0) + ((size_t)b2 * 1024 + q0) * 1024;
#pragma unroll
        for (int kt = 0; kt < 4; ++kt) {
            int k = w * 128 + kt * 32 + q5;
#pragma unroll
            for (int r = 0; r < 16; ++r) {
                int qq = (r & 3) + 8 * (r >> 2) + 4 * hi;
                pb[(size_t)qq * 1024 + k] = (_Float16)aacc[kt][r];
            }
        }
    }
}

// ---------------------------------------------------------------------------
// A_avg = (part0 + part1) / 16   (deterministic, fully overwrites output)
// ---------------------------------------------------------------------------
__global__ void add_avg(const _Float16* __restrict__ p0,
                        const _Float16* __restrict__ p1,
                        float* __restrict__ out) {
    int i = blockIdx.x * blockDim.x + threadIdx.x;  // groups of 8
    f16x8 a = ((const f16x8*)p0)[i];
    f16x8 b = ((const f16x8*)p1)[i];
    f32x4 r0, r1;
#pragma unroll
    for (int j = 0; j < 4; ++j) r0[j] = ((float)a[j] + (float)b[j]) * 0.0625f;
#pragma unroll
    for (int j = 0; j < 4; ++j) r1[j] = ((float)a[4 + j] + (float)b[4 + j]) * 0.0625f;
    *(f32x4*)&out[8 * i] = r0;
    *(f32x4*)&out[8 * i + 4] = r1;
}

// ---------------------------------------------------------------------------
extern "C" void kernel_launch(void* const* d_in, const int* in_sizes, int n_in,
                              void* d_out, int out_size, void* d_ws, size_t ws_size,
                              hipStream_t stream) {
    if (ws_size < ((size_t)46 << 20)) return;  // need 46 MB scratch

    const float* Q  = (const float*)d_in[0];
    const float* K  = (const float*)d_in[1];
    const float* Wq = (const float*)d_in[2];
    const float* bq = (const float*)d_in[3];
    const float* Wk = (const float*)d_in[4];
    const float* bk = (const float*)d_in[5];
    const float* Wv = (const float*)d_in[6];
    const float* bv = (const float*)d_in[7];

    char* ws = (char*)d_ws;
    _Float16* Qh  = (_Float16*)(ws);                      //  8 MB
    _Float16* Kh  = (_Float16*)(ws + ((size_t)8 << 20));  //  8 MB
    _Float16* Wqh = (_Float16*)(ws + ((size_t)16 << 20)); //  2 MB
    _Float16* Wkh = (_Float16*)(ws + ((size_t)18 << 20)); //  2 MB
    _Float16* Wvh = (_Float16*)(ws + ((size_t)20 << 20)); //  2 MB
    _Float16* qo  = (_Float16*)(ws + ((size_t)22 << 20)); //  8 MB
    _Float16* ko  = (_Float16*)(ws + ((size_t)30 << 20)); //  8 MB
    _Float16* vT  = (_Float16*)(ws + ((size_t)38 << 20)); //  8 MB
    // partials alias Qh/Kh (dead after proj_gemm)
    _Float16* part0 = (_Float16*)(ws);                    //  8 MB
    _Float16* part1 = (_Float16*)(ws + ((size_t)8 << 20)); // 8 MB

    float* O = (float*)d_out;
    float* Aavg = O + (size_t)4 * 1024 * 1024;

    // 1) convert inputs to fp16 (dst region is contiguous: Qh..Wvh)
    cvt_all<<<dim3(1441792 / 256), 256, 0, stream>>>(Q, K, Wq, Wk, Wv, Qh);

    // 2) three projection GEMMs in one launch (z selects)
    proj_gemm<<<dim3(32, 8, 3), 256, 0, stream>>>(Qh, Kh, Wqh, Wkh, Wvh,
                                                  bq, bk, bv, qo, ko, vT);

    // 3) fused attention: 256 blocks x 512 threads (partials need no memset:
    //    every element has exactly one writer)
    const int SMEM = 69632 + 2048;  // 71680 B
    hipFuncSetAttribute((const void*)attn, hipFuncAttributeMaxDynamicSharedMemorySize, SMEM);
    attn<<<dim3(256), 512, SMEM, stream>>>(qo, ko, vT, O, part0, part1);

    // 4) A_avg = (part0 + part1) / 16
    add_avg<<<dim3(2048), 256, 0, stream>>>(part0, part1, Aavg);
}

// Round 7
// 118.712 us; speedup vs baseline: 1.5755x; 1.3046x over previous
//
#include <hip/hip_runtime.h>
#include <hip/hip_bf16.h>
#include <hip/hip_fp16.h>

typedef _Float16 f16x8 __attribute__((ext_vector_type(8)));
typedef _Float16 f16x4 __attribute__((ext_vector_type(4)));
typedef _Float16 f16x2 __attribute__((ext_vector_type(2)));
typedef float f32x4 __attribute__((ext_vector_type(4)));
typedef float f32x16 __attribute__((ext_vector_type(16)));
typedef unsigned int u32x4 __attribute__((ext_vector_type(4)));

#define MFMA16(a, b, c) __builtin_amdgcn_mfma_f32_16x16x32_f16(a, b, c, 0, 0, 0)
#define MFMA32(a, b, c) __builtin_amdgcn_mfma_f32_32x32x16_f16(a, b, c, 0, 0, 0)

// log2(e) / sqrt(1024)
#define C1 0.045084220027780106f

#define VMCNT0 asm volatile("s_waitcnt vmcnt(0)" ::: "memory")
#define LGKM0 asm volatile("s_waitcnt lgkmcnt(0)" ::: "memory")

// ---------------------------------------------------------------------------
// convert f32 -> fp16 for Q, K, Wq, Wk, Wv into one contiguous ws region
// ---------------------------------------------------------------------------
__global__ void cvt_all(const float* __restrict__ Q, const float* __restrict__ K,
                        const float* __restrict__ Wq, const float* __restrict__ Wk,
                        const float* __restrict__ Wv, _Float16* __restrict__ dst) {
    int i = blockIdx.x * blockDim.x + threadIdx.x;  // i indexes groups of 8 f32
    const float* s;
    int off;
    if (i < 524288)       { s = Q;  off = 0;       }
    else if (i < 1048576) { s = K;  off = 524288;  }
    else if (i < 1179648) { s = Wq; off = 1048576; }
    else if (i < 1310720) { s = Wk; off = 1179648; }
    else                  { s = Wv; off = 1310720; }
    int j = i - off;
    float4 a = ((const float4*)s)[2 * j];
    float4 b = ((const float4*)s)[2 * j + 1];
    f16x8 h;
    h[0] = (_Float16)a.x; h[1] = (_Float16)a.y; h[2] = (_Float16)a.z; h[3] = (_Float16)a.w;
    h[4] = (_Float16)b.x; h[5] = (_Float16)b.y; h[6] = (_Float16)b.z; h[7] = (_Float16)b.w;
    ((f16x8*)dst)[i] = h;
}

// ---------------------------------------------------------------------------
// projection GEMM: C[m,n] = A[m,:]·W[n,:] + bias[n]
// z=0: q, z=1: k, z=2: v written TILED-transposed: vT[b*16+h][n>>5][d 64][n&31]
// ---------------------------------------------------------------------------
__device__ __forceinline__ void gl_lds16(const void* g, void* l) {
    __builtin_amdgcn_global_load_lds(
        (const __attribute__((address_space(1))) void*)g,
        (__attribute__((address_space(3))) void*)l, 16, 0, 0);
}

__global__ __launch_bounds__(256) void proj_gemm(
    const _Float16* __restrict__ Qh, const _Float16* __restrict__ Kh,
    const _Float16* __restrict__ Wqh, const _Float16* __restrict__ Wkh,
    const _Float16* __restrict__ Wvh,
    const float* __restrict__ bq, const float* __restrict__ bk,
    const float* __restrict__ bv,
    _Float16* __restrict__ qo, _Float16* __restrict__ ko,
    _Float16* __restrict__ vT) {
    const int z = blockIdx.z;
    const _Float16* A = (z == 0) ? Qh : Kh;
    const _Float16* W = (z == 0) ? Wqh : (z == 1 ? Wkh : Wvh);
    const float* bias = (z == 0) ? bq : (z == 1 ? bk : bv);

    __shared__ __align__(16) _Float16 At[128 * 32];
    __shared__ __align__(16) _Float16 Bt[128 * 32];

    const int tid = threadIdx.x;
    const int w = tid >> 6, lane = tid & 63;
    const int g = lane >> 4, c = lane & 15;
    const int m0 = blockIdx.x * 128, n0 = blockIdx.y * 128;
    const int wm = (w & 1) * 64, wn = (w >> 1) * 64;
    const int srow = w * 32 + (lane >> 2);
    const int scol = (lane & 3) * 8;  // in halves

    f32x4 acc[4][4] = {};

    for (int k0 = 0; k0 < 1024; k0 += 32) {
        __syncthreads();
#pragma unroll
        for (int t = 0; t < 2; ++t) {
            int r = srow + t * 16;
            gl_lds16(A + (size_t)(m0 + r) * 1024 + k0 + scol, &At[(w * 2 + t) * 512]);
            gl_lds16(W + (size_t)(n0 + r) * 1024 + k0 + scol, &Bt[(w * 2 + t) * 512]);
        }
        __syncthreads();
        f16x8 af[4], bf[4];
#pragma unroll
        for (int mt = 0; mt < 4; ++mt) af[mt] = *(const f16x8*)&At[(wm + mt * 16 + c) * 32 + g * 8];
#pragma unroll
        for (int nt = 0; nt < 4; ++nt) bf[nt] = *(const f16x8*)&Bt[(wn + nt * 16 + c) * 32 + g * 8];
#pragma unroll
        for (int mt = 0; mt < 4; ++mt)
#pragma unroll
            for (int nt = 0; nt < 4; ++nt)
                acc[mt][nt] = MFMA16(af[mt], bf[nt], acc[mt][nt]);
    }

    if (z != 2) {
        _Float16* C = (z == 0) ? qo : ko;
#pragma unroll
        for (int mt = 0; mt < 4; ++mt)
#pragma unroll
            for (int nt = 0; nt < 4; ++nt) {
                int col = n0 + wn + nt * 16 + c;
                float bb = bias[col];
#pragma unroll
                for (int i = 0; i < 4; ++i) {
                    int row = m0 + wm + mt * 16 + g * 4 + i;
                    C[(size_t)row * 1024 + col] = (_Float16)(acc[mt][nt][i] + bb);
                }
            }
    } else {
#pragma unroll
        for (int mt = 0; mt < 4; ++mt)
#pragma unroll
            for (int nt = 0; nt < 4; ++nt) {
                int col = n0 + wn + nt * 16 + c;
                int hh = col >> 6, dd = col & 63;
                float bb = bias[col];
                int row0 = m0 + wm + mt * 16 + g * 4;
                int bbi = row0 >> 10, nn = row0 & 1023;
                f16x4 pk;
#pragma unroll
                for (int i = 0; i < 4; ++i) pk[i] = (_Float16)(acc[mt][nt][i] + bb);
                // tiled: [b*16+h][nn>>5][dd][nn&31]
                size_t off = (((size_t)(bbi * 16 + hh) * 32 + (nn >> 5)) * 64 + dd) * 32 + (nn & 31);
                *(f16x4*)&vT[off] = pk;
            }
    }
}

// ---------------------------------------------------------------------------
// fused attention v7: 512 threads (8 waves). Same math as v6 (swapped QK^T,
// pack+half-wave exchange, MFMA-avg, non-atomic partials) but ALL operand
// loads are coalesced global_load_lds staging + XOR-swizzled ds_read_b128
// (v6 was L1-transaction-bound: 64 scattered lines per fragment load).
//  - K: per-wave private 4KB slot, single-buffered, pipelined (read frags ->
//    lgkmcnt(0) -> issue next stage -> MFMA).
//  - V: per-wave private 4KB slot from the new tiled vT layout (contiguous).
//  - Q: 4KB shared slot, staged by waves 0-3, prefetched one pair ahead.
//  - Swizzle via pre-swizzled per-lane GLOBAL source (LDS dest stays linear),
//    read back with slot ^= (row & 7) (K/Q, 128B rows) / (row & 3) (V, 64B).
// ---------------------------------------------------------------------------
__global__ __launch_bounds__(512, 2) void attn(
    const _Float16* __restrict__ qh, const _Float16* __restrict__ kh,
    const _Float16* __restrict__ vT, float* __restrict__ O,
    _Float16* __restrict__ part0, _Float16* __restrict__ part1) {
    extern __shared__ __align__(16) char smem[];
    float* Obuf = (float*)smem;                      // [8][32][68] f32 = 69632
    _Float16* Kbuf = (_Float16*)(smem + 69632);      // 8 x 4KB = 32768
    _Float16* Vbuf = (_Float16*)(smem + 102400);     // 8 x 4KB = 32768
    _Float16* Qbuf = (_Float16*)(smem + 135168);     // 4KB
    float* red_m = (float*)(smem + 139264);          // [8][32]
    float* red_l = (float*)(smem + 140288);          // [8][32]  total 141312

    const int tid = threadIdx.x, w = tid >> 6, lane = tid & 63;
    const int q5 = lane & 31, hi = lane >> 5;

    // XCD-aware: group = f & 7 -> all 32 q-tiles of a group on one XCD
    const int f = blockIdx.x;
    const int grp = f & 7, q0 = (f >> 3) * 32;
    const int chunk = grp & 1, b2 = grp >> 1;

    // staging lane->slot maps (source pre-swizzle; LDS dest linear)
    const int krow8 = lane >> 3;                  // row within 8-row chunk
    const int kslot = (lane & 7) ^ krow8;         // K/Q: slot ^ (row&7)
    const int vrow16 = lane >> 2;                 // row within 16-row chunk
    const int vslot = (lane & 3) ^ (vrow16 & 3);  // V: slot ^ (row&3)
    const int kswz = q5 & 7, vswz = q5 & 3;

    _Float16* kb_l = Kbuf + w * 2048;  // halves
    _Float16* vb_l = Vbuf + w * 2048;

    // Bsel B-fragments: Bsel[ks](k,n) = (k == n&15 && n>>4 == ks)
    f16x8 bsel[2];
#pragma unroll
    for (int ks = 0; ks < 2; ++ks)
#pragma unroll
        for (int j = 0; j < 8; ++j)
            bsel[ks][j] = (hi * 8 + j == (q5 & 15) && (q5 >> 4) == ks)
                              ? (_Float16)1.0f : (_Float16)0.0f;

    f32x16 aacc[4] = {};

    // ---- prologue: stage Q(p0) + K0(p0) ----
    {
        const int mm = b2 * 16 + chunk * 8;
        const _Float16* qb0 = qh + (size_t)(mm & 3) * 1048576 + (mm >> 2) * 64;
        const _Float16* kb0 = kh + (size_t)(mm & 3) * 1048576 + (mm >> 2) * 64;
        if (w < 4)
            gl_lds16(qb0 + (size_t)(q0 + w * 8 + krow8) * 1024 + kslot * 8, Qbuf + w * 512);
#pragma unroll
        for (int i = 0; i < 4; ++i)
            gl_lds16(kb0 + (size_t)(w * 128 + i * 8 + krow8) * 1024 + kslot * 8, kb_l + i * 512);
    }
    __syncthreads();

#pragma unroll 1
    for (int p = 0; p < 8; ++p) {
        const int m = b2 * 16 + chunk * 8 + p;
        const int b = m & 3, h = m >> 2;
        const _Float16* kb = kh + (size_t)b * 1048576 + h * 64;
        const _Float16* vtb = vT + (size_t)(b * 16 + h) * 65536;

        // ---- pipelined: reduce + store O of pair p-1 ----
        if (p) {
            int mp = m - 1; int bp = mp & 3, hp = mp >> 2;
            int qq = tid >> 4, dd = (tid & 15) * 4;
            f32x4 acc = {};
#pragma unroll
            for (int buf = 0; buf < 8; ++buf) {
                f32x4 v = *(f32x4*)&Obuf[buf * 2176 + qq * 68 + dd];
                acc += v;
            }
            *(f32x4*)(O + (size_t)bp * 1048576 + (size_t)(q0 + qq) * 1024 + hp * 64 + dd) = acc;
        }

        // ---- phase 1: QK^T from staged LDS ----
        f16x8 qf[4];
        f32x16 s[4] = {};
#pragma unroll
        for (int kt = 0; kt < 4; ++kt) {
            VMCNT0;  // K_kt (and Q at kt==0) landed
            if (kt == 0) {
#pragma unroll
                for (int dc = 0; dc < 4; ++dc)
                    qf[dc] = *(const f16x8*)&Qbuf[q5 * 64 + ((dc * 2 + hi) ^ kswz) * 8];
            }
            f16x8 kf[4];
#pragma unroll
            for (int dc = 0; dc < 4; ++dc)
                kf[dc] = *(const f16x8*)&kb_l[q5 * 64 + ((dc * 2 + hi) ^ kswz) * 8];
            LGKM0;  // frag reads done before overwriting the slot
            if (kt < 3) {
#pragma unroll
                for (int i = 0; i < 4; ++i)
                    gl_lds16(kb + (size_t)(w * 128 + (kt + 1) * 32 + i * 8 + krow8) * 1024 + kslot * 8,
                             kb_l + i * 512);
            } else {
#pragma unroll
                for (int i = 0; i < 4; ++i)
                    gl_lds16(vtb + (w * 4) * 2048 + (i * 16 + vrow16) * 32 + vslot * 8,
                             vb_l + i * 512);
            }
#pragma unroll
            for (int dc = 0; dc < 4; ++dc) s[kt] = MFMA32(kf[dc], qf[dc], s[kt]);
        }

        // ---- local (wave) max + exp + sum ----
        float pm = -3.0e38f;
#pragma unroll
        for (int kt = 0; kt < 4; ++kt)
#pragma unroll
            for (int r = 0; r < 16; ++r) pm = fmaxf(pm, s[kt][r]);
        pm = fmaxf(pm, __shfl_xor(pm, 32, 64));
        float l = 0.f;
#pragma unroll
        for (int kt = 0; kt < 4; ++kt)
#pragma unroll
            for (int r = 0; r < 16; ++r) {
                float e = exp2f((s[kt][r] - pm) * C1);
                s[kt][r] = e; l += e;
            }
        l += __shfl_xor(l, 32, 64);
        if (hi == 0) { red_m[w * 32 + q5] = pm; red_l[w * 32 + q5] = l; }
        __syncthreads();  // A

        // ---- global fixup over 8 waves ----
        float mr[4], lr[4], M = -3.0e38f;
#pragma unroll
        for (int t = 0; t < 4; ++t) {
            int wv = hi * 4 + t;
            mr[t] = red_m[wv * 32 + q5];
            lr[t] = red_l[wv * 32 + q5];
            M = fmaxf(M, mr[t]);
        }
        M = fmaxf(M, __shfl_xor(M, 32, 64));
        float L = 0.f;
#pragma unroll
        for (int t = 0; t < 4; ++t) L += lr[t] * exp2f((mr[t] - M) * C1);
        L += __shfl_xor(L, 32, 64);
        const float sc = exp2f((pm - M) * C1) / L;

        // ---- pack P = e*sc -> f16 pairs, half-wave exchange -> av ----
        u32x4 av[4][2];
#pragma unroll
        for (int kt = 0; kt < 4; ++kt) {
            unsigned pw[8];
#pragma unroll
            for (int r2 = 0; r2 < 8; ++r2) {
                f16x2 t2;
                t2[0] = (_Float16)(s[kt][2 * r2] * sc);
                t2[1] = (_Float16)(s[kt][2 * r2 + 1] * sc);
                pw[r2] = __builtin_bit_cast(unsigned, t2);
            }
            unsigned recv[2][2];
#pragma unroll
            for (int ks = 0; ks < 2; ++ks)
#pragma unroll
                for (int d = 0; d < 2; ++d) {
                    unsigned send = hi ? pw[4 * ks + d] : pw[4 * ks + 2 + d];
                    recv[ks][d] = (unsigned)__shfl_xor((int)send, 32, 64);
                }
#pragma unroll
            for (int ks = 0; ks < 2; ++ks) {
                unsigned own0 = hi ? pw[4 * ks + 2] : pw[4 * ks + 0];
                unsigned own1 = hi ? pw[4 * ks + 3] : pw[4 * ks + 1];
                u32x4 a;
                a[0] = hi ? recv[ks][0] : own0;
                a[1] = hi ? recv[ks][1] : own1;
                a[2] = hi ? own0 : recv[ks][0];
                a[3] = hi ? own1 : recv[ks][1];
                av[kt][ks] = a;
            }
        }

        // ---- phase 2: PV + MFMA-avg from staged V ----
        f32x16 o0 = {}, o1 = {};
#pragma unroll
        for (int kt = 0; kt < 4; ++kt) {
            VMCNT0;  // V_kt landed
            f16x8 vf[2][2];
#pragma unroll
            for (int dh = 0; dh < 2; ++dh)
#pragma unroll
                for (int ks = 0; ks < 2; ++ks)
                    vf[dh][ks] = *(const f16x8*)&vb_l[(dh * 32 + q5) * 32 +
                                                      ((ks * 2 + hi) ^ vswz) * 8];
            LGKM0;
            if (kt < 3) {
#pragma unroll
                for (int i = 0; i < 4; ++i)
                    gl_lds16(vtb + (w * 4 + kt + 1) * 2048 + (i * 16 + vrow16) * 32 + vslot * 8,
                             vb_l + i * 512);
            }
            if (kt == 2 && p < 7) {
                const int mn = m + 1;
                const _Float16* qbn = qh + (size_t)(mn & 3) * 1048576 + (mn >> 2) * 64;
                const _Float16* kbn = kh + (size_t)(mn & 3) * 1048576 + (mn >> 2) * 64;
                if (w < 4)
                    gl_lds16(qbn + (size_t)(q0 + w * 8 + krow8) * 1024 + kslot * 8, Qbuf + w * 512);
#pragma unroll
                for (int i = 0; i < 4; ++i)
                    gl_lds16(kbn + (size_t)(w * 128 + i * 8 + krow8) * 1024 + kslot * 8,
                             kb_l + i * 512);
            }
#pragma unroll
            for (int ks = 0; ks < 2; ++ks) {
                f16x8 pa = __builtin_bit_cast(f16x8, av[kt][ks]);
                o0 = MFMA32(pa, vf[0][ks], o0);
                o1 = MFMA32(pa, vf[1][ks], o1);
            }
            aacc[kt] = MFMA32(__builtin_bit_cast(f16x8, av[kt][0]), bsel[0], aacc[kt]);
            aacc[kt] = MFMA32(__builtin_bit_cast(f16x8, av[kt][1]), bsel[1], aacc[kt]);
        }

        // ---- O partials to Obuf ----
        float* ob = Obuf + w * 2176;
#pragma unroll
        for (int r = 0; r < 16; ++r) {
            int qq = (r & 3) + 8 * (r >> 2) + 4 * hi;
            ob[qq * 68 + q5] = o0[r];
            ob[qq * 68 + 32 + q5] = o1[r];
        }
        __syncthreads();  // C
    }

    // ---- final reduce + store O for pair 7 ----
    {
        int mp = b2 * 16 + chunk * 8 + 7; int bp = mp & 3, hp = mp >> 2;
        int qq = tid >> 4, dd = (tid & 15) * 4;
        f32x4 acc = {};
#pragma unroll
        for (int buf = 0; buf < 8; ++buf) {
            f32x4 v = *(f32x4*)&Obuf[buf * 2176 + qq * 68 + dd];
            acc += v;
        }
        *(f32x4*)(O + (size_t)bp * 1048576 + (size_t)(q0 + qq) * 1024 + hp * 64 + dd) = acc;
    }

    // ---- A_avg tail: non-atomic f16 partial stores ----
    {
        _Float16* pb = (chunk ? part1 : part0) + ((size_t)b2 * 1024 + q0) * 1024;
#pragma unroll
        for (int kt = 0; kt < 4; ++kt) {
            int k = w * 128 + kt * 32 + q5;
#pragma unroll
            for (int r = 0; r < 16; ++r) {
                int qq = (r & 3) + 8 * (r >> 2) + 4 * hi;
                pb[(size_t)qq * 1024 + k] = (_Float16)aacc[kt][r];
            }
        }
    }
}

// ---------------------------------------------------------------------------
// A_avg = (part0 + part1) / 16
// ---------------------------------------------------------------------------
__global__ void add_avg(const _Float16* __restrict__ p0,
                        const _Float16* __restrict__ p1,
                        float* __restrict__ out) {
    int i = blockIdx.x * blockDim.x + threadIdx.x;  // groups of 8
    f16x8 a = ((const f16x8*)p0)[i];
    f16x8 b = ((const f16x8*)p1)[i];
    f32x4 r0, r1;
#pragma unroll
    for (int j = 0; j < 4; ++j) r0[j] = ((float)a[j] + (float)b[j]) * 0.0625f;
#pragma unroll
    for (int j = 0; j < 4; ++j) r1[j] = ((float)a[4 + j] + (float)b[4 + j]) * 0.0625f;
    *(f32x4*)&out[8 * i] = r0;
    *(f32x4*)&out[8 * i + 4] = r1;
}

// ---------------------------------------------------------------------------
extern "C" void kernel_launch(void* const* d_in, const int* in_sizes, int n_in,
                              void* d_out, int out_size, void* d_ws, size_t ws_size,
                              hipStream_t stream) {
    if (ws_size < ((size_t)46 << 20)) return;  // need 46 MB scratch

    const float* Q  = (const float*)d_in[0];
    const float* K  = (const float*)d_in[1];
    const float* Wq = (const float*)d_in[2];
    const float* bq = (const float*)d_in[3];
    const float* Wk = (const float*)d_in[4];
    const float* bk = (const float*)d_in[5];
    const float* Wv = (const float*)d_in[6];
    const float* bv = (const float*)d_in[7];

    char* ws = (char*)d_ws;
    _Float16* Qh  = (_Float16*)(ws);                      //  8 MB
    _Float16* Kh  = (_Float16*)(ws + ((size_t)8 << 20));  //  8 MB
    _Float16* Wqh = (_Float16*)(ws + ((size_t)16 << 20)); //  2 MB
    _Float16* Wkh = (_Float16*)(ws + ((size_t)18 << 20)); //  2 MB
    _Float16* Wvh = (_Float16*)(ws + ((size_t)20 << 20)); //  2 MB
    _Float16* qo  = (_Float16*)(ws + ((size_t)22 << 20)); //  8 MB
    _Float16* ko  = (_Float16*)(ws + ((size_t)30 << 20)); //  8 MB
    _Float16* vT  = (_Float16*)(ws + ((size_t)38 << 20)); //  8 MB (tiled)
    // partials alias Qh/Kh (dead after proj_gemm)
    _Float16* part0 = (_Float16*)(ws);                     // 8 MB
    _Float16* part1 = (_Float16*)(ws + ((size_t)8 << 20)); // 8 MB

    float* O = (float*)d_out;
    float* Aavg = O + (size_t)4 * 1024 * 1024;

    // 1) convert inputs to fp16
    cvt_all<<<dim3(1441792 / 256), 256, 0, stream>>>(Q, K, Wq, Wk, Wv, Qh);

    // 2) three projection GEMMs
    proj_gemm<<<dim3(32, 8, 3), 256, 0, stream>>>(Qh, Kh, Wqh, Wkh, Wvh,
                                                  bq, bk, bv, qo, ko, vT);

    // 3) fused attention: 256 blocks x 512 threads, 141312 B LDS
    const int SMEM = 141312;
    hipFuncSetAttribute((const void*)attn, hipFuncAttributeMaxDynamicSharedMemorySize, SMEM);
    attn<<<dim3(256), 512, SMEM, stream>>>(qo, ko, vT, O, part0, part1);

    // 4) A_avg = (part0 + part1) / 16
    add_avg<<<dim3(2048), 256, 0, stream>>>(part0, part1, Aavg);
}